// Round 1
// baseline (747.871 us; speedup 1.0000x reference)
//
#include <hip/hip_runtime.h>
#include <hip/hip_bf16.h>
#include <math.h>

#define BATCH   32
#define DIM     4096
#define NH      32
#define NKV     8
#define GQ      4
#define HD      128
#define BS      16
#define MAXSEQ  2048
#define NBLK_TBL 128                 // MAX_SEQ / BLOCK_SIZE
#define SCALE_F 0.08838834764831845f // 128^-0.5

#define CHUNK_D   512                // split-K chunk for GEMMs
#define NCHUNK_D  8
#define ATT_CHUNK 256                // tokens per attention partial block
#define ATT_NCHUNK 8
#define ATT_TILE  32
#define QKV_COLS  6144               // 4096 q + 1024 k + 1024 v

// ---------------------------------------------------------------------------
// Split-K GEMM: partial[chunk][b][col] = sum_{d in chunk} X[b][d] * W[d][col]
// W is a column-concat of up to 3 row-major (D x n_i) matrices.
// Block: 256 thr = 32 colgrps (4 cols each) x 8 bgrps (4 batches each).
// ---------------------------------------------------------------------------
__global__ __launch_bounds__(256) void gemm_split(
    const float* __restrict__ X,
    const float* __restrict__ W0, int ld0, int n0,
    const float* __restrict__ W1, int ld1, int n1,
    const float* __restrict__ W2, int ld2, int n2,
    int OT, float* __restrict__ partial)
{
    __shared__ float xs[BATCH][CHUNK_D];   // 64 KB
    const int tid = threadIdx.x;
    const int colbase = blockIdx.x * 128;
    const int d0 = blockIdx.y * CHUNK_D;

    // stage x[:, d0:d0+512] into LDS, coalesced float4
    #pragma unroll
    for (int rep = 0; rep < 16; ++rep) {
        int f4 = rep * 256 + tid;          // 0..4095 (32 rows x 128 f4)
        int b  = f4 >> 7;
        int j  = (f4 & 127) << 2;
        *(float4*)&xs[b][j] = *(const float4*)(X + b * DIM + d0 + j);
    }
    __syncthreads();

    const float* W; int ld, off;
    if (colbase < n0)           { W = W0; ld = ld0; off = colbase; }
    else if (colbase < n0 + n1) { W = W1; ld = ld1; off = colbase - n0; }
    else                        { W = W2; ld = ld2; off = colbase - n0 - n1; }

    const int colgrp = tid & 31;
    const int bgrp   = tid >> 5;
    const float* Wp = W + off + colgrp * 4;

    float acc[4][4];
    #pragma unroll
    for (int i = 0; i < 4; ++i)
        #pragma unroll
        for (int j = 0; j < 4; ++j) acc[i][j] = 0.f;

    for (int j4 = 0; j4 < CHUNK_D / 4; ++j4) {
        const int d = d0 + j4 * 4;
        float4 w0 = *(const float4*)(Wp + (size_t)(d + 0) * ld);
        float4 w1 = *(const float4*)(Wp + (size_t)(d + 1) * ld);
        float4 w2 = *(const float4*)(Wp + (size_t)(d + 2) * ld);
        float4 w3 = *(const float4*)(Wp + (size_t)(d + 3) * ld);
        #pragma unroll
        for (int bb = 0; bb < 4; ++bb) {
            float4 xv = *(const float4*)&xs[bgrp * 4 + bb][j4 * 4];
            acc[bb][0] += xv.x * w0.x + xv.y * w1.x + xv.z * w2.x + xv.w * w3.x;
            acc[bb][1] += xv.x * w0.y + xv.y * w1.y + xv.z * w2.y + xv.w * w3.y;
            acc[bb][2] += xv.x * w0.z + xv.y * w1.z + xv.z * w2.z + xv.w * w3.z;
            acc[bb][3] += xv.x * w0.w + xv.y * w1.w + xv.z * w2.w + xv.w * w3.w;
        }
    }

    const int chunk = blockIdx.y;
    #pragma unroll
    for (int bb = 0; bb < 4; ++bb) {
        int b = bgrp * 4 + bb;
        float4 o = make_float4(acc[bb][0], acc[bb][1], acc[bb][2], acc[bb][3]);
        *(float4*)(partial + ((size_t)chunk * BATCH + b) * OT + colbase + colgrp * 4) = o;
    }
}

// ---------------------------------------------------------------------------
// Reduce QKV partials, apply RoPE to q and k, write k/v into caches, q to ws.
// One block per batch.
// ---------------------------------------------------------------------------
__global__ __launch_bounds__(256) void rope_cache_update(
    const float* __restrict__ qkvp,   // [NCHUNK_D][BATCH][6144]
    const int* __restrict__ ctxlen, const int* __restrict__ btab,
    float* __restrict__ q_out,        // [BATCH][4096]
    float* __restrict__ kcache, float* __restrict__ vcache)
{
    __shared__ float buf[QKV_COLS];   // 24 KB
    const int b = blockIdx.x, tid = threadIdx.x;
    for (int c = tid; c < QKV_COLS; c += 256) {
        float s = 0.f;
        #pragma unroll
        for (int ch = 0; ch < NCHUNK_D; ++ch)
            s += qkvp[((size_t)ch * BATCH + b) * QKV_COLS + c];
        buf[c] = s;
    }
    __syncthreads();
    const int pos  = ctxlen[b] - 1;
    const int slot = btab[b * NBLK_TBL + (pos >> 4)] * BS + (pos & 15);
    const float fpos = (float)pos;
    const float NEG_LN_BASE_OVER_HALF = -0.14391156831212787f; // -ln(10000)/64

    // q rope: 32 heads x 64 pairs
    for (int p = tid; p < NH * 64; p += 256) {
        int h = p >> 6, i = p & 63;
        float x1 = buf[h * HD + i];
        float x2 = buf[h * HD + i + 64];
        float ang = fpos * expf(NEG_LN_BASE_OVER_HALF * (float)i);
        float sn, cs;
        sincosf(ang, &sn, &cs);
        q_out[b * 4096 + h * HD + i]      = x1 * cs - x2 * sn;
        q_out[b * 4096 + h * HD + i + 64] = x1 * sn + x2 * cs;
    }
    // k rope + cache write
    for (int p = tid; p < NKV * 64; p += 256) {
        int kv = p >> 6, i = p & 63;
        float x1 = buf[4096 + kv * HD + i];
        float x2 = buf[4096 + kv * HD + i + 64];
        float ang = fpos * expf(NEG_LN_BASE_OVER_HALF * (float)i);
        float sn, cs;
        sincosf(ang, &sn, &cs);
        kcache[((size_t)slot * NKV + kv) * HD + i]      = x1 * cs - x2 * sn;
        kcache[((size_t)slot * NKV + kv) * HD + i + 64] = x1 * sn + x2 * cs;
    }
    // v cache write (no rope)
    for (int p = tid; p < NKV * HD; p += 256) {
        int kv = p >> 7, i = p & 127;
        vcache[((size_t)slot * NKV + kv) * HD + i] = buf[5120 + kv * HD + i];
    }
}

// ---------------------------------------------------------------------------
// Flash-decode attention partial. Grid (B, NKV, ATT_NCHUNK); block 256.
// Partial layout per (b,kv,c): [4 heads][132] = o[0:128], m@128, l@129, pad.
// LDS rows stride 132 floats (== 4 mod 32 -> consecutive lanes hit
// consecutive bank groups on b128 reads).
// ---------------------------------------------------------------------------
__global__ __launch_bounds__(256) void attn_partial(
    const float* __restrict__ q,      // [BATCH][4096]
    const float* __restrict__ kcache, const float* __restrict__ vcache,
    const int* __restrict__ btab, const int* __restrict__ ctxlen,
    float* __restrict__ part)
{
    const int b = blockIdx.x, kv = blockIdx.y, c = blockIdx.z;
    const int tid = threadIdx.x;
    const int ctx = ctxlen[b];
    const int start = c * ATT_CHUNK;
    const int end = min(ctx, start + ATT_CHUNK);
    float* pp = part + ((size_t)(b * NKV + kv) * ATT_NCHUNK + c) * (4 * 132);
    if (start >= end) {
        for (int i = tid; i < 4 * 132; i += 256) {
            int r = i - (i / 132) * 132;
            pp[i] = (r == 128) ? -1e30f : 0.f;
        }
        return;
    }
    __shared__ float Ks[ATT_TILE][132];
    __shared__ float Vs[ATT_TILE][132];
    __shared__ float qs[4][HD];
    __shared__ float s_lds[4][ATT_TILE];
    __shared__ float p_lds[4][ATT_TILE];
    __shared__ float alpha_l[4];

    for (int i = tid; i < 4 * HD; i += 256)
        qs[i >> 7][i & 127] = q[b * 4096 + kv * GQ * HD + i];

    float m_run = -1e30f, l_run = 0.f;          // live in tid<4 only
    float4 oacc = make_float4(0.f, 0.f, 0.f, 0.f); // live in tid<128 only
    __syncthreads();

    for (int t0 = start; t0 < end; t0 += ATT_TILE) {
        const int nt = min(ATT_TILE, end - t0);
        // stage K,V tiles (coalesced float4)
        for (int idx = tid; idx < nt * 32; idx += 256) {
            int tt = idx >> 5, f4 = idx & 31;
            int tok = t0 + tt;
            int slot = btab[b * NBLK_TBL + (tok >> 4)] * BS + (tok & 15);
            size_t base = ((size_t)slot * NKV + kv) * HD + f4 * 4;
            *(float4*)&Ks[tt][f4 * 4] = *(const float4*)(kcache + base);
            *(float4*)&Vs[tt][f4 * 4] = *(const float4*)(vcache + base);
        }
        __syncthreads();
        // scores: thread (t, h) over 128 dims
        if (tid < 128) {
            int t = tid & 31, h = tid >> 5;
            float s = -1e30f;
            if (t < nt) {
                float sum = 0.f;
                #pragma unroll
                for (int d4 = 0; d4 < 32; ++d4) {
                    float4 kk = *(const float4*)&Ks[t][d4 * 4];
                    float4 qq = *(const float4*)&qs[h][d4 * 4];
                    sum += kk.x * qq.x + kk.y * qq.y + kk.z * qq.z + kk.w * qq.w;
                }
                s = sum * SCALE_F;
            }
            s_lds[h][t] = s;
        }
        __syncthreads();
        // online softmax bookkeeping: one lane per head
        if (tid < 4) {
            int h = tid;
            float mt = -1e30f;
            #pragma unroll
            for (int t = 0; t < ATT_TILE; ++t) mt = fmaxf(mt, s_lds[h][t]);
            float mn = fmaxf(m_run, mt);
            float al = __expf(m_run - mn);
            float ls = 0.f;
            #pragma unroll
            for (int t = 0; t < ATT_TILE; ++t) {
                float pv = __expf(s_lds[h][t] - mn);
                p_lds[h][t] = pv;
                ls += pv;
            }
            l_run = l_run * al + ls;
            m_run = mn;
            alpha_l[h] = al;
        }
        __syncthreads();
        // PV: thread (h, d4) accumulates o[h][4*d4 .. +3]
        if (tid < 128) {
            int h = tid >> 5, d4 = tid & 31;
            float al = alpha_l[h];
            oacc.x *= al; oacc.y *= al; oacc.z *= al; oacc.w *= al;
            for (int t = 0; t < nt; ++t) {
                float pv = p_lds[h][t];
                float4 vv = *(const float4*)&Vs[t][d4 * 4];
                oacc.x += pv * vv.x; oacc.y += pv * vv.y;
                oacc.z += pv * vv.z; oacc.w += pv * vv.w;
            }
        }
        __syncthreads();
    }
    if (tid < 128) {
        int h = tid >> 5, d4 = tid & 31;
        *(float4*)(pp + h * 132 + d4 * 4) = oacc;
    }
    if (tid < 4) {
        pp[tid * 132 + 128] = m_run;
        pp[tid * 132 + 129] = l_run;
    }
}

// ---------------------------------------------------------------------------
// Combine attention chunk partials -> attn_out[b][head*128+d]
// ---------------------------------------------------------------------------
__global__ __launch_bounds__(128) void attn_reduce(
    const float* __restrict__ part, float* __restrict__ attn_out)
{
    const int b = blockIdx.x, kv = blockIdx.y;
    const int d = threadIdx.x;  // 0..127
    const float* base = part + (size_t)(b * NKV + kv) * ATT_NCHUNK * (4 * 132);
    #pragma unroll
    for (int h = 0; h < 4; ++h) {
        float M = -1e30f;
        #pragma unroll
        for (int c2 = 0; c2 < ATT_NCHUNK; ++c2)
            M = fmaxf(M, base[c2 * (4 * 132) + h * 132 + 128]);
        float L = 0.f, o = 0.f;
        #pragma unroll
        for (int c2 = 0; c2 < ATT_NCHUNK; ++c2) {
            float m = base[c2 * (4 * 132) + h * 132 + 128];
            float l = base[c2 * (4 * 132) + h * 132 + 129];
            float w = __expf(m - M);
            L += l * w;
            o += base[c2 * (4 * 132) + h * 132 + d] * w;
        }
        attn_out[b * 4096 + (kv * GQ + h) * HD + d] = o / L;
    }
}

// ---------------------------------------------------------------------------
// Reduce o-proj partials -> d_out
// ---------------------------------------------------------------------------
__global__ __launch_bounds__(256) void final_reduce(
    const float* __restrict__ part, float* __restrict__ out)
{
    const int b = blockIdx.x;
    for (int c = threadIdx.x; c < DIM; c += 256) {
        float s = 0.f;
        #pragma unroll
        for (int ch = 0; ch < NCHUNK_D; ++ch)
            s += part[((size_t)ch * BATCH + b) * DIM + c];
        out[b * DIM + c] = s;
    }
}

extern "C" void kernel_launch(void* const* d_in, const int* in_sizes, int n_in,
                              void* d_out, int out_size, void* d_ws, size_t ws_size,
                              hipStream_t stream)
{
    const float* x  = (const float*)d_in[0];
    const float* Wq = (const float*)d_in[1];
    const float* Wk = (const float*)d_in[2];
    const float* Wv = (const float*)d_in[3];
    const float* Wo = (const float*)d_in[4];
    float* kc = (float*)d_in[5];       // cache writes are idempotent; harness
    float* vc = (float*)d_in[6];       // restores d_in before every launch
    const int* bt  = (const int*)d_in[7];
    const int* ctx = (const int*)d_in[8];
    float* out = (float*)d_out;

    // workspace layout (floats), total ~15.9 MB
    float* ws = (float*)d_ws;
    float* qkvp      = ws;                                   // 8*32*6144
    float* q_ws      = qkvp + (size_t)NCHUNK_D * BATCH * QKV_COLS;
    float* attn_part = q_ws + (size_t)BATCH * 4096;          // 2048*528
    float* attn_o    = attn_part + (size_t)BATCH * NKV * ATT_NCHUNK * 4 * 132;
    float* oprojp    = attn_o + (size_t)BATCH * 4096;        // 8*32*4096

    gemm_split<<<dim3(48, 8), 256, 0, stream>>>(
        x, Wq, 4096, 4096, Wk, 1024, 1024, Wv, 1024, 1024, QKV_COLS, qkvp);
    rope_cache_update<<<32, 256, 0, stream>>>(qkvp, ctx, bt, q_ws, kc, vc);
    attn_partial<<<dim3(BATCH, NKV, ATT_NCHUNK), 256, 0, stream>>>(
        q_ws, kc, vc, bt, ctx, attn_part);
    attn_reduce<<<dim3(BATCH, NKV), 128, 0, stream>>>(attn_part, attn_o);
    gemm_split<<<dim3(32, 8), 256, 0, stream>>>(
        attn_o, Wo, 4096, 4096, nullptr, 0, 0, nullptr, 0, 0, DIM, oprojp);
    final_reduce<<<32, 256, 0, stream>>>(oprojp, out);
}

// Round 2
// 671.900 us; speedup vs baseline: 1.1131x; 1.1131x over previous
//
#include <hip/hip_runtime.h>
#include <hip/hip_bf16.h>
#include <math.h>

#define BATCH   32
#define DIM     4096
#define NH      32
#define NKV     8
#define GQ      4
#define HD      128
#define BS      16
#define MAXSEQ  2048
#define NBLK_TBL 128                 // MAX_SEQ / BLOCK_SIZE
#define SCALE_F 0.08838834764831845f // 128^-0.5

#define CHUNK_D   128                // split-K chunk for GEMMs
#define NCHUNK_D  32
#define ATT_CHUNK 256                // tokens per attention partial block
#define ATT_NCHUNK 8
#define ATT_TILE  32
#define QKV_COLS  6144               // 4096 q + 1024 k + 1024 v

// ---------------------------------------------------------------------------
// Split-K GEMM: partial[chunk][b][col] = sum_{d in chunk} X[b][d] * W[d][col]
// W is a column-concat of up to 3 row-major (D x n_i) matrices.
// Block: 256 thr = 32 colgrps (4 cols each) x 8 bgrps (4 batches each).
// CHUNK_D=128 -> 16KB LDS, grid 1536/1024 blocks (6/4 per CU) for latency
// hiding on the once-streamed W (round-0 had 1.5 blocks/CU -> 10x off BW).
// ---------------------------------------------------------------------------
__global__ __launch_bounds__(256) void gemm_split(
    const float* __restrict__ X,
    const float* __restrict__ W0, int ld0, int n0,
    const float* __restrict__ W1, int ld1, int n1,
    const float* __restrict__ W2, int ld2, int n2,
    int OT, float* __restrict__ partial)
{
    __shared__ float xs[BATCH][CHUNK_D];   // 16 KB
    const int tid = threadIdx.x;
    const int colbase = blockIdx.x * 128;
    const int d0 = blockIdx.y * CHUNK_D;

    // stage x[:, d0:d0+128] into LDS, coalesced float4
    #pragma unroll
    for (int rep = 0; rep < 4; ++rep) {
        int f4 = rep * 256 + tid;          // 0..1023 (32 rows x 32 f4)
        int b  = f4 >> 5;
        int j  = (f4 & 31) << 2;
        *(float4*)&xs[b][j] = *(const float4*)(X + b * DIM + d0 + j);
    }
    __syncthreads();

    const float* W; int ld, off;
    if (colbase < n0)           { W = W0; ld = ld0; off = colbase; }
    else if (colbase < n0 + n1) { W = W1; ld = ld1; off = colbase - n0; }
    else                        { W = W2; ld = ld2; off = colbase - n0 - n1; }

    const int colgrp = tid & 31;
    const int bgrp   = tid >> 5;
    const float* Wp = W + off + colgrp * 4;

    float acc[4][4];
    #pragma unroll
    for (int i = 0; i < 4; ++i)
        #pragma unroll
        for (int j = 0; j < 4; ++j) acc[i][j] = 0.f;

    for (int j4 = 0; j4 < CHUNK_D / 4; ++j4) {
        const int d = d0 + j4 * 4;
        float4 w0 = *(const float4*)(Wp + (size_t)(d + 0) * ld);
        float4 w1 = *(const float4*)(Wp + (size_t)(d + 1) * ld);
        float4 w2 = *(const float4*)(Wp + (size_t)(d + 2) * ld);
        float4 w3 = *(const float4*)(Wp + (size_t)(d + 3) * ld);
        #pragma unroll
        for (int bb = 0; bb < 4; ++bb) {
            float4 xv = *(const float4*)&xs[bgrp * 4 + bb][j4 * 4];
            acc[bb][0] += xv.x * w0.x + xv.y * w1.x + xv.z * w2.x + xv.w * w3.x;
            acc[bb][1] += xv.x * w0.y + xv.y * w1.y + xv.z * w2.y + xv.w * w3.y;
            acc[bb][2] += xv.x * w0.z + xv.y * w1.z + xv.z * w2.z + xv.w * w3.z;
            acc[bb][3] += xv.x * w0.w + xv.y * w1.w + xv.z * w2.w + xv.w * w3.w;
        }
    }

    const int chunk = blockIdx.y;
    #pragma unroll
    for (int bb = 0; bb < 4; ++bb) {
        int b = bgrp * 4 + bb;
        float4 o = make_float4(acc[bb][0], acc[bb][1], acc[bb][2], acc[bb][3]);
        *(float4*)(partial + ((size_t)chunk * BATCH + b) * OT + colbase + colgrp * 4) = o;
    }
}

// ---------------------------------------------------------------------------
// Reduce QKV partials, apply RoPE to q and k, write k/v into caches, q to ws.
// Grid (BATCH, 6): each block owns 1024 contiguous cols (8 heads).
// seg 0..3 = q heads, seg 4 = k, seg 5 = v.
// ---------------------------------------------------------------------------
__global__ __launch_bounds__(256) void rope_cache_update(
    const float* __restrict__ qkvp,   // [NCHUNK_D][BATCH][6144]
    const int* __restrict__ ctxlen, const int* __restrict__ btab,
    float* __restrict__ q_out,        // [BATCH][4096]
    float* __restrict__ kcache, float* __restrict__ vcache)
{
    __shared__ float buf[1024];
    const int b = blockIdx.x, seg = blockIdx.y, tid = threadIdx.x;
    const int cbase = seg * 1024;
    for (int c = tid; c < 1024; c += 256) {
        float s = 0.f;
        #pragma unroll
        for (int ch = 0; ch < NCHUNK_D; ++ch)
            s += qkvp[((size_t)ch * BATCH + b) * QKV_COLS + cbase + c];
        buf[c] = s;
    }
    __syncthreads();
    const int pos  = ctxlen[b] - 1;
    const int slot = btab[b * NBLK_TBL + (pos >> 4)] * BS + (pos & 15);
    const float fpos = (float)pos;
    const float NEG_LN_BASE_OVER_HALF = -0.14391156831212787f; // -ln(10000)/64

    if (seg < 4) {           // 8 q heads, rope
        for (int p = tid; p < 8 * 64; p += 256) {
            int h = p >> 6, i = p & 63;
            float x1 = buf[h * HD + i];
            float x2 = buf[h * HD + i + 64];
            float ang = fpos * __expf(NEG_LN_BASE_OVER_HALF * (float)i);
            float sn, cs;
            __sincosf(ang, &sn, &cs);
            q_out[b * 4096 + cbase + h * HD + i]      = x1 * cs - x2 * sn;
            q_out[b * 4096 + cbase + h * HD + i + 64] = x1 * sn + x2 * cs;
        }
    } else if (seg == 4) {   // k: rope + cache write
        for (int p = tid; p < NKV * 64; p += 256) {
            int kv = p >> 6, i = p & 63;
            float x1 = buf[kv * HD + i];
            float x2 = buf[kv * HD + i + 64];
            float ang = fpos * __expf(NEG_LN_BASE_OVER_HALF * (float)i);
            float sn, cs;
            __sincosf(ang, &sn, &cs);
            kcache[((size_t)slot * NKV + kv) * HD + i]      = x1 * cs - x2 * sn;
            kcache[((size_t)slot * NKV + kv) * HD + i + 64] = x1 * sn + x2 * cs;
        }
    } else {                 // v: cache write
        for (int p = tid; p < NKV * HD; p += 256) {
            int kv = p >> 7, i = p & 127;
            vcache[((size_t)slot * NKV + kv) * HD + i] = buf[p];
        }
    }
}

// ---------------------------------------------------------------------------
// Flash-decode attention partial. Grid (B, NKV, ATT_NCHUNK); block 256.
// Wave w = head w (GQ=4). Online softmax fully in registers via shfl_xor —
// no serial section, no LDS for m/l/alpha. 2 barriers per 32-token tile.
// K tile rows padded to 132 floats (keeps lane-per-row b128 reads at the
// 8-cyc LDS floor); V rows read whole-row-per-wave (conflict-free unpadded).
// LDS 35.4KB -> 4 blocks/CU.
// Partial layout per (b,kv,c): [4 heads][132] = o[0:128], m@128, l@129, pad.
// ---------------------------------------------------------------------------
__global__ __launch_bounds__(256) void attn_partial(
    const float* __restrict__ q,      // [BATCH][4096]
    const float* __restrict__ kcache, const float* __restrict__ vcache,
    const int* __restrict__ btab, const int* __restrict__ ctxlen,
    float* __restrict__ part)
{
    const int b = blockIdx.x, kv = blockIdx.y, c = blockIdx.z;
    const int tid = threadIdx.x;
    const int ctx = ctxlen[b];
    const int start = c * ATT_CHUNK;
    const int end = min(ctx, start + ATT_CHUNK);
    float* pp = part + ((size_t)(b * NKV + kv) * ATT_NCHUNK + c) * (4 * 132);
    if (start >= end) {
        for (int i = tid; i < 4 * 132; i += 256) {
            int r = i - (i / 132) * 132;
            pp[i] = (r == 128) ? -1e30f : 0.f;
        }
        return;
    }
    __shared__ float Ks[ATT_TILE][132];   // 16.9 KB
    __shared__ float Vs[ATT_TILE][128];   // 16 KB
    __shared__ float qs[4][HD];           // 2 KB
    __shared__ float p_lds[4][ATT_TILE];  // 0.5 KB

    for (int i = tid; i < 4 * HD; i += 256)
        qs[i >> 7][i & 127] = q[b * 4096 + kv * GQ * HD + i];

    const int h    = tid >> 6;   // wave index == head
    const int lane = tid & 63;

    float m_run = -1e30f, l_run = 0.f;              // replicated across wave
    float2 oacc = make_float2(0.f, 0.f);            // dims 2*lane, 2*lane+1

    for (int t0 = start; t0 < end; t0 += ATT_TILE) {
        const int nt = min(ATT_TILE, end - t0);
        // stage K,V tiles (coalesced float4); all 256 threads
        for (int idx = tid; idx < nt * 32; idx += 256) {
            int tt = idx >> 5, f4 = idx & 31;
            int tok = t0 + tt;
            int slot = btab[b * NBLK_TBL + (tok >> 4)] * BS + (tok & 15);
            size_t base = ((size_t)slot * NKV + kv) * HD + f4 * 4;
            *(float4*)&Ks[tt][f4 * 4] = *(const float4*)(kcache + base);
            *(float4*)&Vs[tt][f4 * 4] = *(const float4*)(vcache + base);
        }
        __syncthreads();

        // scores: lane t (t < nt) dots K[t][:] . q[h][:]
        float s = -1e30f;
        if (lane < nt) {
            float sum = 0.f;
            #pragma unroll
            for (int d4 = 0; d4 < 32; ++d4) {
                float4 kk = *(const float4*)&Ks[lane][d4 * 4];
                float4 qq = *(const float4*)&qs[h][d4 * 4];
                sum += kk.x * qq.x + kk.y * qq.y + kk.z * qq.z + kk.w * qq.w;
            }
            s = sum * SCALE_F;
        }
        // wave-wide online softmax (all in registers)
        float mt = s;
        #pragma unroll
        for (int off = 1; off < 64; off <<= 1)
            mt = fmaxf(mt, __shfl_xor(mt, off));
        float mn = fmaxf(m_run, mt);
        float al = __expf(m_run - mn);
        float p  = (lane < nt) ? __expf(s - mn) : 0.f;
        float ps = p;
        #pragma unroll
        for (int off = 1; off < 64; off <<= 1)
            ps += __shfl_xor(ps, off);
        l_run = l_run * al + ps;
        m_run = mn;
        p_lds[h][lane & (ATT_TILE - 1)] = p;   // lanes >=nt write p=0 (ok)
        if (lane < ATT_TILE) p_lds[h][lane] = p;

        // PV: lane = dim-pair index; same-wave LDS dep on p_lds (no barrier)
        oacc.x *= al; oacc.y *= al;
        for (int t = 0; t < nt; ++t) {
            float pv = p_lds[h][t];
            float2 vv = *(const float2*)&Vs[t][lane * 2];
            oacc.x += pv * vv.x; oacc.y += pv * vv.y;
        }
        __syncthreads();   // Ks/Vs safe to overwrite next tile
    }
    *(float2*)(pp + h * 132 + lane * 2) = oacc;
    if (lane == 0) {
        pp[h * 132 + 128] = m_run;
        pp[h * 132 + 129] = l_run;
    }
}

// ---------------------------------------------------------------------------
// Combine attention chunk partials -> attn_out[b][head*128+d]
// ---------------------------------------------------------------------------
__global__ __launch_bounds__(128) void attn_reduce(
    const float* __restrict__ part, float* __restrict__ attn_out)
{
    const int b = blockIdx.x, kv = blockIdx.y;
    const int d = threadIdx.x;  // 0..127
    const float* base = part + (size_t)(b * NKV + kv) * ATT_NCHUNK * (4 * 132);
    #pragma unroll
    for (int h = 0; h < 4; ++h) {
        float M = -1e30f;
        #pragma unroll
        for (int c2 = 0; c2 < ATT_NCHUNK; ++c2)
            M = fmaxf(M, base[c2 * (4 * 132) + h * 132 + 128]);
        float L = 0.f, o = 0.f;
        #pragma unroll
        for (int c2 = 0; c2 < ATT_NCHUNK; ++c2) {
            float m = base[c2 * (4 * 132) + h * 132 + 128];
            float l = base[c2 * (4 * 132) + h * 132 + 129];
            float w = __expf(m - M);
            L += l * w;
            o += base[c2 * (4 * 132) + h * 132 + d] * w;
        }
        attn_out[b * 4096 + (kv * GQ + h) * HD + d] = o / L;
    }
}

// ---------------------------------------------------------------------------
// Reduce o-proj partials -> d_out.  Grid (BATCH, 4), 1024 cols per block.
// ---------------------------------------------------------------------------
__global__ __launch_bounds__(256) void final_reduce(
    const float* __restrict__ part, float* __restrict__ out)
{
    const int b = blockIdx.x;
    const int cb = blockIdx.y * 1024;
    for (int c = threadIdx.x; c < 1024; c += 256) {
        float s = 0.f;
        #pragma unroll
        for (int ch = 0; ch < NCHUNK_D; ++ch)
            s += part[((size_t)ch * BATCH + b) * DIM + cb + c];
        out[b * DIM + cb + c] = s;
    }
}

extern "C" void kernel_launch(void* const* d_in, const int* in_sizes, int n_in,
                              void* d_out, int out_size, void* d_ws, size_t ws_size,
                              hipStream_t stream)
{
    const float* x  = (const float*)d_in[0];
    const float* Wq = (const float*)d_in[1];
    const float* Wk = (const float*)d_in[2];
    const float* Wv = (const float*)d_in[3];
    const float* Wo = (const float*)d_in[4];
    float* kc = (float*)d_in[5];       // cache writes are idempotent; harness
    float* vc = (float*)d_in[6];       // restores d_in before every launch
    const int* bt  = (const int*)d_in[7];
    const int* ctx = (const int*)d_in[8];
    float* out = (float*)d_out;

    // workspace layout (floats), ~47 MB
    float* ws = (float*)d_ws;
    float* qkvp      = ws;                                   // 32*32*6144
    float* q_ws      = qkvp + (size_t)NCHUNK_D * BATCH * QKV_COLS;
    float* attn_part = q_ws + (size_t)BATCH * 4096;          // 2048*528
    float* attn_o    = attn_part + (size_t)BATCH * NKV * ATT_NCHUNK * 4 * 132;
    float* oprojp    = attn_o + (size_t)BATCH * 4096;        // 32*32*4096

    gemm_split<<<dim3(48, NCHUNK_D), 256, 0, stream>>>(
        x, Wq, 4096, 4096, Wk, 1024, 1024, Wv, 1024, 1024, QKV_COLS, qkvp);
    rope_cache_update<<<dim3(32, 6), 256, 0, stream>>>(qkvp, ctx, bt, q_ws, kc, vc);
    attn_partial<<<dim3(BATCH, NKV, ATT_NCHUNK), 256, 0, stream>>>(
        q_ws, kc, vc, bt, ctx, attn_part);
    attn_reduce<<<dim3(BATCH, NKV), 128, 0, stream>>>(attn_part, attn_o);
    gemm_split<<<dim3(32, NCHUNK_D), 256, 0, stream>>>(
        attn_o, Wo, 4096, 4096, nullptr, 0, 0, nullptr, 0, 0, DIM, oprojp);
    final_reduce<<<dim3(32, 4), 256, 0, stream>>>(oprojp, out);
}